// Round 3
// baseline (434.486 us; speedup 1.0000x reference)
//
#include <hip/hip_runtime.h>
#include <cstdint>
#include <cstddef>

#define B_  64
#define O_  36
#define D_  512
#define P_  (O_*O_)     // 1296 pairs per batch
#define BO_ (B_*O_)     // 2304 object rows

typedef short s8v __attribute__((ext_vector_type(8)));   // 8 bf16 (4 VGPRs)
typedef float f4v __attribute__((ext_vector_type(4)));   // MFMA accumulator

// RNE float->bf16 split: x ~= hi + lo with ~16 mantissa bits total.
__device__ __forceinline__ void bsplit(float x, short& hi, short& lo) {
    unsigned u = __float_as_uint(x);
    unsigned r = (u + 0x7FFFu + ((u >> 16) & 1u)) >> 16;
    hi = (short)r;
    float hf = __uint_as_float(r << 16);
    float d = x - hf;
    unsigned u2 = __float_as_uint(d);
    unsigned r2 = (u2 + 0x7FFFu + ((u2 >> 16) & 1u)) >> 16;
    lo = (short)r2;
}

// ---------------------------------------------------------------------------
// Kernel 0a: split W2 (fp32 [512][512]) into bf16 hi/lo arrays (same layout).
// ---------------------------------------------------------------------------
__global__ __launch_bounds__(256) void w2split(
    const float* __restrict__ W2, short* __restrict__ hi, short* __restrict__ lo)
{
    const int i = (blockIdx.x * 256 + threadIdx.x) * 4;   // 256 blocks cover 512*512
    const float4 w = *(const float4*)&W2[i];
    short h0, l0, h1, l1, h2, l2, h3, l3;
    bsplit(w.x, h0, l0); bsplit(w.y, h1, l1);
    bsplit(w.z, h2, l2); bsplit(w.w, h3, l3);
    *(short4*)&hi[i] = make_short4(h0, h1, h2, h3);
    *(short4*)&lo[i] = make_short4(l0, l1, l2, l3);
}

// ---------------------------------------------------------------------------
// Kernel 0b: repack+split W1 (fp32 [512][1024]) into bf16 hi/lo [1024][512]:
//   W1c[n][d] = W1[n&511][(n>=512)*512 + d]   (n<512 -> U cols, else V cols)
// ---------------------------------------------------------------------------
__global__ __launch_bounds__(256) void w1split(
    const float* __restrict__ W1, short* __restrict__ hi, short* __restrict__ lo)
{
    const int i = (blockIdx.x * 256 + threadIdx.x) * 4;   // 512 blocks cover 1024*512
    const int n = i >> 9, d = i & 511;
    const float4 w = *(const float4*)&W1[(size_t)(n & 511) * 1024 + ((n >> 9) << 9) + d];
    short h0, l0, h1, l1, h2, l2, h3, l3;
    bsplit(w.x, h0, l0); bsplit(w.y, h1, l1);
    bsplit(w.z, h2, l2); bsplit(w.w, h3, l3);
    *(short4*)&hi[i] = make_short4(h0, h1, h2, h3);
    *(short4*)&lo[i] = make_short4(l0, l1, l2, l3);
}

// ---------------------------------------------------------------------------
// Kernel 1: U/V GEMM via split-bf16 MFMA.
//   U[r][g] = sum_d objs[r][d]*W1[g][d];  V[r][g] = sum_d objs[r][d]*W1[g][512+d]
// Combined col space n in [0,1024): n<512 -> U, else V (via repacked W1c).
// Block: 256 thr (4 waves), tile 128 rows x 128 cols, BK=32. 2304 = 18*128
// exactly -> no row guards. Wave (wr,wc) owns a 64x64 quadrant (4x4 frags).
// ---------------------------------------------------------------------------
__global__ __launch_bounds__(256, 2) void uv_mfma(
    const float* __restrict__ objs,
    const short* __restrict__ W1h, const short* __restrict__ W1l,
    float* __restrict__ U, float* __restrict__ V)
{
    __shared__ short Ah[128 * 40];
    __shared__ short Al[128 * 40];
    __shared__ short Bh[128 * 40];
    __shared__ short Bl[128 * 40];

    const int tid  = threadIdx.x;
    const int lane = tid & 63;
    const int wid  = tid >> 6;
    const int wr   = wid >> 1, wc = wid & 1;
    const int rowbase = blockIdx.y * 128;   // 18 tiles over 2304
    const int colbase = blockIdx.x * 128;   // 8 tiles over 1024

    const int srow = tid >> 1;
    const int skq  = (tid & 1) * 8;
    const float* Xrow  = objs + (size_t)(rowbase + srow) * 512;
    const short* Whrow = W1h + (size_t)(colbase + srow) * 512;
    const short* Wlrow = W1l + (size_t)(colbase + srow) * 512;

    const int fr = lane & 15;           // frag row (A) / col (B)
    const int sl = (lane >> 4) * 8;     // k element offset
    const int abase = (wr * 64 + fr) * 40 + sl;
    const int bbase = (wc * 64 + fr) * 40 + sl;

    f4v acc[4][4];
    const f4v zero = {0.f, 0.f, 0.f, 0.f};
    #pragma unroll
    for (int i = 0; i < 4; ++i)
        #pragma unroll
        for (int j = 0; j < 4; ++j) acc[i][j] = zero;

    for (int kt = 0; kt < 512; kt += 32) {
        __syncthreads();
        #pragma unroll
        for (int pass = 0; pass < 2; ++pass) {
            const int kq = skq + pass * 16;   // 0/8/16/24
            const float4 x0 = *(const float4*)&Xrow[kt + kq];
            const float4 x1 = *(const float4*)&Xrow[kt + kq + 4];
            float hx[8] = {x0.x, x0.y, x0.z, x0.w, x1.x, x1.y, x1.z, x1.w};
            s8v hi8, lo8;
            #pragma unroll
            for (int j = 0; j < 8; ++j) { short h, l; bsplit(hx[j], h, l); hi8[j] = h; lo8[j] = l; }
            *(s8v*)&Ah[srow * 40 + kq] = hi8;
            *(s8v*)&Al[srow * 40 + kq] = lo8;
            *(s8v*)&Bh[srow * 40 + kq] = *(const s8v*)&Whrow[kt + kq];
            *(s8v*)&Bl[srow * 40 + kq] = *(const s8v*)&Wlrow[kt + kq];
        }
        __syncthreads();

        s8v ah[4], al[4], bh[4], bl[4];
        #pragma unroll
        for (int f = 0; f < 4; ++f) {
            ah[f] = *(const s8v*)&Ah[abase + f * 640];
            al[f] = *(const s8v*)&Al[abase + f * 640];
            bh[f] = *(const s8v*)&Bh[bbase + f * 640];
            bl[f] = *(const s8v*)&Bl[bbase + f * 640];
        }
        #pragma unroll
        for (int fm = 0; fm < 4; ++fm)
            #pragma unroll
            for (int fn = 0; fn < 4; ++fn) {
                acc[fm][fn] = __builtin_amdgcn_mfma_f32_16x16x32_bf16(ah[fm], bh[fn], acc[fm][fn], 0, 0, 0);
                acc[fm][fn] = __builtin_amdgcn_mfma_f32_16x16x32_bf16(ah[fm], bl[fn], acc[fm][fn], 0, 0, 0);
                acc[fm][fn] = __builtin_amdgcn_mfma_f32_16x16x32_bf16(al[fm], bh[fn], acc[fm][fn], 0, 0, 0);
            }
    }

    float* dst = (colbase < 512) ? U : V;
    const int cb = colbase & 511;
    const int r4 = (lane >> 4) * 4;
    #pragma unroll
    for (int fm = 0; fm < 4; ++fm) {
        #pragma unroll
        for (int r = 0; r < 4; ++r) {
            const int row = rowbase + wr * 64 + fm * 16 + r4 + r;
            float* drow = &dst[(size_t)row * 512 + cb + wc * 64 + fr];
            #pragma unroll
            for (int fn = 0; fn < 4; ++fn) drow[fn * 16] = acc[fm][fn][r];
        }
    }
}

// ---------------------------------------------------------------------------
// Kernel 2: pair GEMM via split-bf16 MFMA.
//   h[p][k'] = relu(U[b,m][k'] + V[b,k][k'] + b1[k'])     (p = k*36+m)
//   x[p][n]  = relu(sum_k' h*W2[n][k'] + b2[n]) -> xout, plus col-sums -> s
// Block: 256 thr (4 waves), tile 128 pairs x 128 cols, BK=32.
// Split product: hi*hi + hi*lo + lo*hi (lo*lo dropped, O(2^-18) rel).
// LDS rows stride 40 bf16 (80 B): uniform 8-access/bank for b128 ops.
// ---------------------------------------------------------------------------
__global__ __launch_bounds__(256, 2) void pair_gemm(
    const float* __restrict__ U, const float* __restrict__ V,
    const float* __restrict__ b1,
    const short* __restrict__ W2h, const short* __restrict__ W2l,
    const float* __restrict__ b2,
    float* __restrict__ xout, float* __restrict__ s)
{
    __shared__ short Ah[128 * 40];
    __shared__ short Al[128 * 40];
    __shared__ short Bh[128 * 40];
    __shared__ short Bl[128 * 40];
    __shared__ float b1s[512];

    const int tid  = threadIdx.x;
    const int lane = tid & 63;
    const int wid  = tid >> 6;
    const int wr   = wid >> 1, wc = wid & 1;
    const int b       = blockIdx.z;
    const int pbase   = blockIdx.y * 128;   // 11 tiles over 1296
    const int colbase = blockIdx.x * 128;   // 4 tiles over 512

    for (int g = tid; g < 512; g += 256) b1s[g] = b1[g];

    const int srow = tid >> 1;
    const int skq  = (tid & 1) * 8;
    const int p    = pbase + srow;
    const bool valid = (p < P_);
    int ki = 0, mi = 0;
    if (valid) { ki = p / O_; mi = p - ki * O_; }
    const float* Urow = U + (size_t)(b * O_ + mi) * 512;
    const float* Vrow = V + (size_t)(b * O_ + ki) * 512;
    const short* W2hrow = W2h + (size_t)(colbase + srow) * 512;
    const short* W2lrow = W2l + (size_t)(colbase + srow) * 512;

    const int fr = lane & 15;
    const int sl = (lane >> 4) * 8;
    const int abase = (wr * 64 + fr) * 40 + sl;
    const int bbase = (wc * 64 + fr) * 40 + sl;

    f4v acc[4][4];
    const f4v zero = {0.f, 0.f, 0.f, 0.f};
    #pragma unroll
    for (int i = 0; i < 4; ++i)
        #pragma unroll
        for (int j = 0; j < 4; ++j) acc[i][j] = zero;

    for (int kt = 0; kt < 512; kt += 32) {
        __syncthreads();
        #pragma unroll
        for (int pass = 0; pass < 2; ++pass) {
            const int kq = skq + pass * 16;   // 0/8/16/24
            s8v hi8, lo8;
            if (valid) {
                const float4 u0 = *(const float4*)&Urow[kt + kq];
                const float4 u1 = *(const float4*)&Urow[kt + kq + 4];
                const float4 v0 = *(const float4*)&Vrow[kt + kq];
                const float4 v1 = *(const float4*)&Vrow[kt + kq + 4];
                const float4 c0 = *(const float4*)&b1s[kt + kq];
                const float4 c1 = *(const float4*)&b1s[kt + kq + 4];
                float hx[8];
                hx[0] = fmaxf(u0.x + v0.x + c0.x, 0.f);
                hx[1] = fmaxf(u0.y + v0.y + c0.y, 0.f);
                hx[2] = fmaxf(u0.z + v0.z + c0.z, 0.f);
                hx[3] = fmaxf(u0.w + v0.w + c0.w, 0.f);
                hx[4] = fmaxf(u1.x + v1.x + c1.x, 0.f);
                hx[5] = fmaxf(u1.y + v1.y + c1.y, 0.f);
                hx[6] = fmaxf(u1.z + v1.z + c1.z, 0.f);
                hx[7] = fmaxf(u1.w + v1.w + c1.w, 0.f);
                #pragma unroll
                for (int j = 0; j < 8; ++j) { short h, l; bsplit(hx[j], h, l); hi8[j] = h; lo8[j] = l; }
            } else {
                #pragma unroll
                for (int j = 0; j < 8; ++j) { hi8[j] = 0; lo8[j] = 0; }
            }
            *(s8v*)&Ah[srow * 40 + kq] = hi8;
            *(s8v*)&Al[srow * 40 + kq] = lo8;
            *(s8v*)&Bh[srow * 40 + kq] = *(const s8v*)&W2hrow[kt + kq];
            *(s8v*)&Bl[srow * 40 + kq] = *(const s8v*)&W2lrow[kt + kq];
        }
        __syncthreads();

        s8v ah[4], al[4], bh[4], bl[4];
        #pragma unroll
        for (int f = 0; f < 4; ++f) {
            ah[f] = *(const s8v*)&Ah[abase + f * 640];
            al[f] = *(const s8v*)&Al[abase + f * 640];
            bh[f] = *(const s8v*)&Bh[bbase + f * 640];
            bl[f] = *(const s8v*)&Bl[bbase + f * 640];
        }
        #pragma unroll
        for (int fm = 0; fm < 4; ++fm)
            #pragma unroll
            for (int fn = 0; fn < 4; ++fn) {
                acc[fm][fn] = __builtin_amdgcn_mfma_f32_16x16x32_bf16(ah[fm], bh[fn], acc[fm][fn], 0, 0, 0);
                acc[fm][fn] = __builtin_amdgcn_mfma_f32_16x16x32_bf16(ah[fm], bl[fn], acc[fm][fn], 0, 0, 0);
                acc[fm][fn] = __builtin_amdgcn_mfma_f32_16x16x32_bf16(al[fm], bh[fn], acc[fm][fn], 0, 0, 0);
            }
    }

    // ---- epilogue: bias+relu, store x_pairs, column sums
    float b2v[4];
    #pragma unroll
    for (int fn = 0; fn < 4; ++fn) b2v[fn] = b2[colbase + wc * 64 + fn * 16 + fr];
    const int r4 = (lane >> 4) * 4;
    float csum[4] = {0.f, 0.f, 0.f, 0.f};
    #pragma unroll
    for (int fm = 0; fm < 4; ++fm) {
        const int prow0 = pbase + wr * 64 + fm * 16 + r4;
        #pragma unroll
        for (int r = 0; r < 4; ++r) {
            const int pp = prow0 + r;
            if (pp < P_) {
                float* xrow = &xout[(size_t)(b * P_ + pp) * 512 + colbase + wc * 64 + fr];
                #pragma unroll
                for (int fn = 0; fn < 4; ++fn) {
                    float x = fmaxf(acc[fm][fn][r] + b2v[fn], 0.f);
                    xrow[fn * 16] = x;
                    csum[fn] += x;
                }
            }
        }
    }
    #pragma unroll
    for (int fn = 0; fn < 4; ++fn) {
        csum[fn] += __shfl_xor(csum[fn], 16);
        csum[fn] += __shfl_xor(csum[fn], 32);
    }
    if (lane < 16) {
        #pragma unroll
        for (int fn = 0; fn < 4; ++fn)
            atomicAdd(&s[b * 512 + colbase + wc * 64 + fn * 16 + lane], csum[fn]);
    }
}

// ---------------------------------------------------------------------------
// Kernel 3: BatchNorm over batch axis (training-mode batch stats, biased var).
// ---------------------------------------------------------------------------
__global__ __launch_bounds__(512) void bn_kernel(
    const float* __restrict__ s, const float* __restrict__ gamma,
    const float* __restrict__ beta, float* __restrict__ sn)
{
    const int g = threadIdx.x;
    float mean = 0.f;
    for (int b = 0; b < B_; ++b) mean += s[b * 512 + g];
    mean *= (1.f / B_);
    float var = 0.f;
    for (int b = 0; b < B_; ++b) { const float d = s[b * 512 + g] - mean; var = fmaf(d, d, var); }
    var *= (1.f / B_);
    const float inv = 1.f / sqrtf(var + 1e-5f);
    const float ga = gamma[g], be = beta[g];
    for (int b = 0; b < B_; ++b)
        sn[b * 512 + g] = (s[b * 512 + g] - mean) * inv * ga + be;
}

// ---------------------------------------------------------------------------
// Kernel 4/5: small dense layer out[b][f] = relu(x[b]·W[f] + bias[f]).
// ---------------------------------------------------------------------------
__global__ __launch_bounds__(256) void mlp512(
    const float* __restrict__ x, const float* __restrict__ W,
    const float* __restrict__ bias, float* __restrict__ out)
{
    __shared__ float xs[512];
    const int b = blockIdx.y;
    const int f = blockIdx.x * 256 + threadIdx.x;
    for (int g = threadIdx.x; g < 512; g += 256) xs[g] = x[b * 512 + g];
    __syncthreads();
    float sum = 0.f;
    #pragma unroll 8
    for (int k = 0; k < 512; k += 4) {
        const float4 w4 = *(const float4*)&W[(size_t)f * 512 + k];
        const float4 x4 = *(const float4*)&xs[k];
        sum = fmaf(w4.x, x4.x, sum); sum = fmaf(w4.y, x4.y, sum);
        sum = fmaf(w4.z, x4.z, sum); sum = fmaf(w4.w, x4.w, sum);
    }
    out[b * 512 + f] = fmaxf(sum + bias[f], 0.f);
}

// ---------------------------------------------------------------------------
extern "C" void kernel_launch(void* const* d_in, const int* in_sizes, int n_in,
                              void* d_out, int out_size, void* d_ws, size_t ws_size,
                              hipStream_t stream)
{
    const float* objs  = (const float*)d_in[0];
    const float* W1    = (const float*)d_in[1];
    const float* b1    = (const float*)d_in[2];
    const float* W2    = (const float*)d_in[3];
    const float* b2    = (const float*)d_in[4];
    const float* gamma = (const float*)d_in[5];
    const float* beta  = (const float*)d_in[6];
    const float* W3    = (const float*)d_in[7];
    const float* b3    = (const float*)d_in[8];
    const float* W4    = (const float*)d_in[9];
    const float* b4    = (const float*)d_in[10];

    float* out  = (float*)d_out;           // agg: [64][512] first
    float* xout = out + B_ * 512;          // x_pairs: [64][1296][512]

    // workspace (floats then bf16): U, V, s, sn, a, W2h/l, W1h/l (~13 MB)
    float* U  = (float*)d_ws;
    float* V  = U  + (size_t)BO_ * 512;
    float* s  = V  + (size_t)BO_ * 512;
    float* sn = s  + B_ * 512;
    float* a  = sn + B_ * 512;
    short* W2h = (short*)(a + B_ * 512);
    short* W2l = W2h + (size_t)512 * 512;
    short* W1h = W2l + (size_t)512 * 512;
    short* W1l = W1h + (size_t)1024 * 512;

    w2split<<<256, 256, 0, stream>>>(W2, W2h, W2l);
    w1split<<<512, 256, 0, stream>>>(W1, W1h, W1l);
    uv_mfma<<<dim3(8, 18), 256, 0, stream>>>(objs, W1h, W1l, U, V);
    hipMemsetAsync(s, 0, B_ * 512 * sizeof(float), stream);
    pair_gemm<<<dim3(4, 11, B_), 256, 0, stream>>>(U, V, b1, W2h, W2l, b2, xout, s);
    bn_kernel<<<1, 512, 0, stream>>>(s, gamma, beta, sn);
    mlp512<<<dim3(2, B_), 256, 0, stream>>>(sn, W3, b3, a);
    mlp512<<<dim3(2, B_), 256, 0, stream>>>(a, W4, b4, out);
}